// Round 10
// baseline (663.630 us; speedup 1.0000x reference)
//
#include <hip/hip_runtime.h>
#include <hip/hip_bf16.h>

// EdgeProbMLP: out[e] = sigmoid( relu( [x*y, x-y] @ W1.T + b1 ) @ W2.T + b2 )
// x = relu(nf[src] @ Wdim.T + bdim), y = same for dst.
// P[n] = relu(proj(nf[n])) precomputed once (bf16, d_ws); per-edge 32x32x16
// MFMA GEMM with W1 in LDS (bf16, XOR-swizzled), rotating in-place prefetch,
// plain (cache-allocating) gather loads (R9: nt->plain was +25%, via L1).
// R10: register diet -> 2 waves/SIMD. R9 ran 1 wave/SIMD (256 VGPR + 64
// acc-AGPR on the unified file): hoisted f32 b1/W2 epilogue constants were
// 128 VGPRs of wave-uniform data. Pack them as bf16 pairs (64 regs, b1 is
// zeros anyway; W2 bf16 = 0.4% rel, harmless) + __launch_bounds__(256,2)
// (cap 2048/(4*2)=256 unified) -> ~222 regs -> 2 blocks/CU, double the
// latency coverage. Falsifier: occupancy ~22% but dur>=190us => TA
// address-divergence bound -> coalesced staging rewrite next.

#define N_NODES 100000
#define N_EDGES 1000000
#define N_TILES 31250

typedef unsigned int u32;
typedef u32   u32x2 __attribute__((ext_vector_type(2)));
typedef u32   u32x4 __attribute__((ext_vector_type(4)));
typedef float f32x4 __attribute__((ext_vector_type(4)));
typedef float f32x16 __attribute__((ext_vector_type(16)));
typedef __bf16 bf16x8 __attribute__((ext_vector_type(8)));

__device__ inline u32 pack2bf(float a, float b) {
    unsigned short ua = __builtin_bit_cast(unsigned short, (__bf16)a);
    unsigned short ub = __builtin_bit_cast(unsigned short, (__bf16)b);
    return (u32)ua | ((u32)ub << 16);
}
__device__ inline float bflo(u32 u) { return __builtin_bit_cast(float, u << 16); }
__device__ inline float bfhi(u32 u) { return __builtin_bit_cast(float, u & 0xFFFF0000u); }

// ---------------------------------------------------------------------------
// Kernel 1: P[n][c] = relu(sum_k nf[n][k] * Wdim[c][k] + bdim[c]), bf16 out.
// (unchanged — ~15us, not the bottleneck)
// ---------------------------------------------------------------------------
__global__ __launch_bounds__(256, 1) void k_project(
    const float* __restrict__ nf, const float* __restrict__ Wdim,
    const float* __restrict__ bdim, unsigned short* __restrict__ P)
{
    __shared__ unsigned char lA[128 * 256];  // 32 KB: Wdim as bf16 [128ch][128k]
    const int t = threadIdx.x;
    for (int ci = t; ci < 2048; ci += 256) {          // 2048 chunks of 8 elems
        const int row = ci >> 4;                      // 16 chunks per 128-elem row
        const int k8 = (ci & 15) << 3;
        const float* wp = Wdim + (row << 7) + k8;
        f32x4 v0 = *(const f32x4*)wp;
        f32x4 v1 = *(const f32x4*)(wp + 4);
        u32x4 pk = { pack2bf(v0[0], v0[1]), pack2bf(v0[2], v0[3]),
                     pack2bf(v1[0], v1[1]), pack2bf(v1[2], v1[3]) };
        int byte = (row << 8) + (k8 << 1);
        byte ^= (row & 15) << 4;
        *(u32x4*)(lA + byte) = pk;
    }
    __syncthreads();

    const int lane = t & 63;
    const int wave = t >> 6;
    const int cc = lane & 31;     // node column
    const int h  = lane >> 5;     // k-half within MFMA
    const int tile = blockIdx.x * 4 + wave;
    if (tile >= 3125) return;
    const int node = (tile << 5) + cc;
    const float* xrow = nf + ((size_t)node << 7);

    f32x4 rv[16];
#pragma unroll
    for (int kt = 0; kt < 8; ++kt) {
        const int kf = (kt << 4) + (h << 3);
        rv[2*kt]   = *(const f32x4*)(xrow + kf);
        rv[2*kt+1] = *(const f32x4*)(xrow + kf + 4);
    }

    f32x16 acc[4] = {};
#pragma unroll
    for (int kt = 0; kt < 8; ++kt) {                  // K = 128 = 8 * 16
        const int kf = (kt << 4) + (h << 3);
        f32x4 v0 = rv[2*kt], v1 = rv[2*kt+1];
        bf16x8 bf;
        bf[0]=(__bf16)v0[0]; bf[1]=(__bf16)v0[1]; bf[2]=(__bf16)v0[2]; bf[3]=(__bf16)v0[3];
        bf[4]=(__bf16)v1[0]; bf[5]=(__bf16)v1[1]; bf[6]=(__bf16)v1[2]; bf[7]=(__bf16)v1[3];
        const int off = kf << 1;                      // byte offset within LDS row
#pragma unroll
        for (int t4 = 0; t4 < 4; ++t4) {
            const int arow = (t4 << 5) + cc;
            const int ab = ((arow << 8) + off) ^ ((arow & 15) << 4);
            bf16x8 af = __builtin_bit_cast(bf16x8, *(const u32x4*)(lA + ab));
            acc[t4] = __builtin_amdgcn_mfma_f32_32x32x16_bf16(af, bf, acc[t4], 0, 0, 0);
        }
    }
    unsigned short* prow = P + ((size_t)node << 7);
#pragma unroll
    for (int t4 = 0; t4 < 4; ++t4) {
#pragma unroll
        for (int q = 0; q < 4; ++q) {
            const int chb = (t4 << 5) + (q << 3) + (h << 2);
            f32x4 bb = *(const f32x4*)(bdim + chb);
            const float h0 = fmaxf(acc[t4][(q << 2) + 0] + bb[0], 0.f);
            const float h1 = fmaxf(acc[t4][(q << 2) + 1] + bb[1], 0.f);
            const float h2 = fmaxf(acc[t4][(q << 2) + 2] + bb[2], 0.f);
            const float h3 = fmaxf(acc[t4][(q << 2) + 3] + bb[3], 0.f);
            u32x2 st = { pack2bf(h0, h1), pack2bf(h2, h3) };
            *(u32x2*)(prow + chb) = st;
        }
    }
}

// ---------------------------------------------------------------------------
// Kernel 2: per-edge MLP, 32 edges per wave-tile, rotating prefetch,
// bf16-packed epilogue constants (64 regs instead of 128).
// ---------------------------------------------------------------------------
struct Rows { u32x4 v[16]; };   // [0..7]=src row chunks, [8..15]=dst row chunks

__global__ __launch_bounds__(256, 2) void k_edge(
    const unsigned short* __restrict__ P,
    const int* __restrict__ ei,          // [2][E] int32
    const float* __restrict__ W1, const float* __restrict__ b1,
    const float* __restrict__ W2, const float* __restrict__ b2,
    float* __restrict__ out)
{
    __shared__ unsigned char lA[128 * 512];  // 64 KB: W1 bf16 [128ch][256k]
    const int t = threadIdx.x;
    for (int ci = t; ci < 4096; ci += 256) {          // 4096 chunks of 8
        const int row = ci >> 5;                      // 32 chunks per 256-elem row
        const int k8 = (ci & 31) << 3;
        const float* wp = W1 + (row << 8) + k8;
        f32x4 v0 = *(const f32x4*)wp;
        f32x4 v1 = *(const f32x4*)(wp + 4);
        u32x4 pk = { pack2bf(v0[0], v0[1]), pack2bf(v0[2], v0[3]),
                     pack2bf(v1[0], v1[1]), pack2bf(v1[2], v1[3]) };
        int byte = (row << 9) + (k8 << 1);
        byte ^= (row & 31) << 4;
        *(u32x4*)(lA + byte) = pk;
    }
    __syncthreads();

    const int lane = t & 63;
    const int wave = t >> 6;
    const int cc = lane & 31;     // edge column within tile
    const int h  = lane >> 5;     // k-half
    const float b2v = b2[0];
    const int stride = gridDim.x << 2;
    const int t0 = blockIdx.x * 4 + wave;             // t0 < 2048 <= N_TILES

    // hoist b1 / W2 once, PACKED as bf16 pairs: 64 regs total (was 128 f32).
    // pair index p = (t4<<3)+(q<<1): covers channels chb..chb+3.
    u32 b1p[32], w2p[32];
#pragma unroll
    for (int t4 = 0; t4 < 4; ++t4) {
#pragma unroll
        for (int q = 0; q < 4; ++q) {
            const int chb = (t4 << 5) + (q << 3) + (h << 2);
            const int p = (t4 << 3) + (q << 1);
            b1p[p]     = pack2bf(b1[chb],     b1[chb + 1]);
            b1p[p + 1] = pack2bf(b1[chb + 2], b1[chb + 3]);
            w2p[p]     = pack2bf(W2[chb],     W2[chb + 1]);
            w2p[p + 1] = pack2bf(W2[chb + 2], W2[chb + 3]);
        }
    }

    Rows A;
    int si, di;                                       // indices for NEXT tile
    {   // prologue: cold gather of tile t0, prefetch ei of t0+stride
        const int e0 = t0 << 5;
        const int s0 = ei[e0 + cc];
        const int d0 = ei[N_EDGES + e0 + cc];
        const unsigned char* ps = (const unsigned char*)(P + ((size_t)s0 << 7));
        const unsigned char* pd = (const unsigned char*)(P + ((size_t)d0 << 7));
#pragma unroll
        for (int kt = 0; kt < 8; ++kt) {
            const int off = (kt << 5) + (h << 4);
            A.v[kt]     = *(const u32x4*)(ps + off);
            A.v[8 + kt] = *(const u32x4*)(pd + off);
        }
        int tt = t0 + stride; tt = tt < N_TILES ? tt : N_TILES - 1;
        si = ei[(tt << 5) + cc];
        di = ei[N_EDGES + (tt << 5) + cc];
    }

    for (int tl = t0; tl < N_TILES; tl += stride) {
        const unsigned char* nps = (const unsigned char*)(P + ((size_t)si << 7));
        const unsigned char* npd = (const unsigned char*)(P + ((size_t)di << 7));

        f32x16 acc[4] = {};
#pragma unroll
        for (int kt = 0; kt < 8; ++kt) {
            const int off = (kt << 5) + (h << 4);
            const u32x4 ux = A.v[kt];
            const u32x4 uy = A.v[8 + kt];
            // rotate: slot kt is dead after the copies above -> refill with
            // tile t+1's chunk kt. Issued ~8 MFMA-blocks before consumption.
            A.v[kt]     = *(const u32x4*)(nps + off);
            A.v[8 + kt] = *(const u32x4*)(npd + off);

            bf16x8 bp, bd;
#pragma unroll
            for (int j = 0; j < 4; ++j) {
                const float x0 = bflo(ux[j]), x1 = bfhi(ux[j]);
                const float y0 = bflo(uy[j]), y1 = bfhi(uy[j]);
                bp[2*j]   = (__bf16)(x0 * y0);
                bp[2*j+1] = (__bf16)(x1 * y1);
                bd[2*j]   = (__bf16)(x0 - y0);
                bd[2*j+1] = (__bf16)(x1 - y1);
            }
#pragma unroll
            for (int t4 = 0; t4 < 4; ++t4) {          // product half: W1[:,0:128]
                const int arow = (t4 << 5) + cc;
                const int ab = ((arow << 9) + off) ^ ((arow & 31) << 4);
                bf16x8 af = __builtin_bit_cast(bf16x8, *(const u32x4*)(lA + ab));
                acc[t4] = __builtin_amdgcn_mfma_f32_32x32x16_bf16(af, bp, acc[t4], 0, 0, 0);
            }
#pragma unroll
            for (int t4 = 0; t4 < 4; ++t4) {          // diff half: W1[:,128:256]
                const int arow = (t4 << 5) + cc;
                const int ab = ((arow << 9) + 256 + off) ^ ((arow & 31) << 4);
                bf16x8 af = __builtin_bit_cast(bf16x8, *(const u32x4*)(lA + ab));
                acc[t4] = __builtin_amdgcn_mfma_f32_32x32x16_bf16(af, bd, acc[t4], 0, 0, 0);
            }
        }

        // epilogue: pure VALU (no vmem loads) + one store
        float partial = 0.f;
#pragma unroll
        for (int t4 = 0; t4 < 4; ++t4) {
#pragma unroll
            for (int q = 0; q < 4; ++q) {
                const int p = (t4 << 3) + (q << 1);
                const u32 bb0 = b1p[p], bb1 = b1p[p + 1];
                const u32 ww0 = w2p[p], ww1 = w2p[p + 1];
                const float h0 = fmaxf(acc[t4][(q << 2) + 0] + bflo(bb0), 0.f);
                const float h1 = fmaxf(acc[t4][(q << 2) + 1] + bfhi(bb0), 0.f);
                const float h2 = fmaxf(acc[t4][(q << 2) + 2] + bflo(bb1), 0.f);
                const float h3 = fmaxf(acc[t4][(q << 2) + 3] + bfhi(bb1), 0.f);
                partial += h0 * bflo(ww0) + h1 * bfhi(ww0)
                         + h2 * bflo(ww1) + h3 * bfhi(ww1);
            }
        }
        partial += __shfl_xor(partial, 32);           // sum the two k-half groups
        const float z = partial + b2v;
        const float prob = 1.0f / (1.0f + __expf(-z));
        if (h == 0) out[(tl << 5) + cc] = prob;

        // advance index prefetch: ei for tile tl + 2*stride
        int tt = tl + 2 * stride; tt = tt < N_TILES ? tt : N_TILES - 1;
        si = ei[(tt << 5) + cc];
        di = ei[N_EDGES + (tt << 5) + cc];
    }
}

extern "C" void kernel_launch(void* const* d_in, const int* in_sizes, int n_in,
                              void* d_out, int out_size, void* d_ws, size_t ws_size,
                              hipStream_t stream) {
    const float* nf   = (const float*)d_in[0];
    const int*   ei   = (const int*)d_in[1];
    const float* Wdim = (const float*)d_in[2];
    const float* bdim = (const float*)d_in[3];
    const float* W1   = (const float*)d_in[4];
    const float* b1   = (const float*)d_in[5];
    const float* W2   = (const float*)d_in[6];
    const float* b2   = (const float*)d_in[7];
    float* out = (float*)d_out;
    unsigned short* P = (unsigned short*)d_ws;        // 100000*128 bf16 = 25.6 MB

    k_project<<<dim3(782), dim3(256), 0, stream>>>(nf, Wdim, bdim, P);
    k_edge<<<dim3(512), dim3(256), 0, stream>>>(P, ei, W1, b1, W2, b2, out);
}

// Round 11
// 483.243 us; speedup vs baseline: 1.3733x; 1.3733x over previous
//
#include <hip/hip_runtime.h>
#include <hip/hip_bf16.h>

// EdgeProbMLP: out[e] = sigmoid( relu( [x*y, x-y] @ W1.T + b1 ) @ W2.T + b2 )
// x = relu(nf[src] @ Wdim.T + bdim), y = same for dst.
// P[n] = relu(proj(nf[n])) precomputed once (bf16, d_ws); per-edge 32x32x16
// MFMA GEMM with W1 in LDS (bf16, XOR-swizzled), rotating in-place prefetch,
// plain (L1-allocating) gathers.
// R11: true register diet. R10 showed the allocator quanta are {64,128,256}:
// 2 waves/SIMD + 64 acc-AGPRs requires VGPR<=128 exactly; R9's live set
// (~217: Rows 64 + b1/W2 consts 64 + temps) spilled at that cap. Fix: move
// b1/W2 to a 1KB f32 LDS side-table (ds_read_b128 at 2 addrs/wave =
// broadcast-free; lgkm path, never drains the vmcnt rotation). Live set ->
// ~120 VGPR + 64 AGPR -> fits (256,2) quanta -> 2 blocks/CU (grid 512 = 2/CU
// exactly). Numerically identical to R9 (same f32 math): absmax must stay
// 3.9e-3. Also a clean single-variable retry of R8's NaN mechanism.

#define N_NODES 100000
#define N_EDGES 1000000
#define N_TILES 31250

typedef unsigned int u32;
typedef u32   u32x2 __attribute__((ext_vector_type(2)));
typedef u32   u32x4 __attribute__((ext_vector_type(4)));
typedef float f32x4 __attribute__((ext_vector_type(4)));
typedef float f32x16 __attribute__((ext_vector_type(16)));
typedef __bf16 bf16x8 __attribute__((ext_vector_type(8)));

__device__ inline u32 pack2bf(float a, float b) {
    unsigned short ua = __builtin_bit_cast(unsigned short, (__bf16)a);
    unsigned short ub = __builtin_bit_cast(unsigned short, (__bf16)b);
    return (u32)ua | ((u32)ub << 16);
}
__device__ inline float bflo(u32 u) { return __builtin_bit_cast(float, u << 16); }
__device__ inline float bfhi(u32 u) { return __builtin_bit_cast(float, u & 0xFFFF0000u); }

// ---------------------------------------------------------------------------
// Kernel 1: P[n][c] = relu(sum_k nf[n][k] * Wdim[c][k] + bdim[c]), bf16 out.
// (unchanged — ~15us, not the bottleneck)
// ---------------------------------------------------------------------------
__global__ __launch_bounds__(256, 1) void k_project(
    const float* __restrict__ nf, const float* __restrict__ Wdim,
    const float* __restrict__ bdim, unsigned short* __restrict__ P)
{
    __shared__ unsigned char lA[128 * 256];  // 32 KB: Wdim as bf16 [128ch][128k]
    const int t = threadIdx.x;
    for (int ci = t; ci < 2048; ci += 256) {          // 2048 chunks of 8 elems
        const int row = ci >> 4;                      // 16 chunks per 128-elem row
        const int k8 = (ci & 15) << 3;
        const float* wp = Wdim + (row << 7) + k8;
        f32x4 v0 = *(const f32x4*)wp;
        f32x4 v1 = *(const f32x4*)(wp + 4);
        u32x4 pk = { pack2bf(v0[0], v0[1]), pack2bf(v0[2], v0[3]),
                     pack2bf(v1[0], v1[1]), pack2bf(v1[2], v1[3]) };
        int byte = (row << 8) + (k8 << 1);
        byte ^= (row & 15) << 4;
        *(u32x4*)(lA + byte) = pk;
    }
    __syncthreads();

    const int lane = t & 63;
    const int wave = t >> 6;
    const int cc = lane & 31;     // node column
    const int h  = lane >> 5;     // k-half within MFMA
    const int tile = blockIdx.x * 4 + wave;
    if (tile >= 3125) return;
    const int node = (tile << 5) + cc;
    const float* xrow = nf + ((size_t)node << 7);

    f32x4 rv[16];
#pragma unroll
    for (int kt = 0; kt < 8; ++kt) {
        const int kf = (kt << 4) + (h << 3);
        rv[2*kt]   = *(const f32x4*)(xrow + kf);
        rv[2*kt+1] = *(const f32x4*)(xrow + kf + 4);
    }

    f32x16 acc[4] = {};
#pragma unroll
    for (int kt = 0; kt < 8; ++kt) {                  // K = 128 = 8 * 16
        const int kf = (kt << 4) + (h << 3);
        f32x4 v0 = rv[2*kt], v1 = rv[2*kt+1];
        bf16x8 bf;
        bf[0]=(__bf16)v0[0]; bf[1]=(__bf16)v0[1]; bf[2]=(__bf16)v0[2]; bf[3]=(__bf16)v0[3];
        bf[4]=(__bf16)v1[0]; bf[5]=(__bf16)v1[1]; bf[6]=(__bf16)v1[2]; bf[7]=(__bf16)v1[3];
        const int off = kf << 1;                      // byte offset within LDS row
#pragma unroll
        for (int t4 = 0; t4 < 4; ++t4) {
            const int arow = (t4 << 5) + cc;
            const int ab = ((arow << 8) + off) ^ ((arow & 15) << 4);
            bf16x8 af = __builtin_bit_cast(bf16x8, *(const u32x4*)(lA + ab));
            acc[t4] = __builtin_amdgcn_mfma_f32_32x32x16_bf16(af, bf, acc[t4], 0, 0, 0);
        }
    }
    unsigned short* prow = P + ((size_t)node << 7);
#pragma unroll
    for (int t4 = 0; t4 < 4; ++t4) {
#pragma unroll
        for (int q = 0; q < 4; ++q) {
            const int chb = (t4 << 5) + (q << 3) + (h << 2);
            f32x4 bb = *(const f32x4*)(bdim + chb);
            const float h0 = fmaxf(acc[t4][(q << 2) + 0] + bb[0], 0.f);
            const float h1 = fmaxf(acc[t4][(q << 2) + 1] + bb[1], 0.f);
            const float h2 = fmaxf(acc[t4][(q << 2) + 2] + bb[2], 0.f);
            const float h3 = fmaxf(acc[t4][(q << 2) + 3] + bb[3], 0.f);
            u32x2 st = { pack2bf(h0, h1), pack2bf(h2, h3) };
            *(u32x2*)(prow + chb) = st;
        }
    }
}

// ---------------------------------------------------------------------------
// Kernel 2: per-edge MLP, 32 edges per wave-tile, rotating prefetch,
// b1/W2 in a 1KB f32 LDS side-table (register diet for 2 waves/SIMD).
// ---------------------------------------------------------------------------
struct Rows { u32x4 v[16]; };   // [0..7]=src row chunks, [8..15]=dst row chunks

__global__ __launch_bounds__(256, 2) void k_edge(
    const unsigned short* __restrict__ P,
    const int* __restrict__ ei,          // [2][E] int32
    const float* __restrict__ W1, const float* __restrict__ b1,
    const float* __restrict__ W2, const float* __restrict__ b2,
    float* __restrict__ out)
{
    __shared__ unsigned char lA[128 * 512];  // 64 KB: W1 bf16 [128ch][256k]
    __shared__ float sb1[128];               // b1 (f32, exact)
    __shared__ float sw2[128];               // W2 (f32, exact)
    const int t = threadIdx.x;
    for (int ci = t; ci < 4096; ci += 256) {          // 4096 chunks of 8
        const int row = ci >> 5;                      // 32 chunks per 256-elem row
        const int k8 = (ci & 31) << 3;
        const float* wp = W1 + (row << 8) + k8;
        f32x4 v0 = *(const f32x4*)wp;
        f32x4 v1 = *(const f32x4*)(wp + 4);
        u32x4 pk = { pack2bf(v0[0], v0[1]), pack2bf(v0[2], v0[3]),
                     pack2bf(v1[0], v1[1]), pack2bf(v1[2], v1[3]) };
        int byte = (row << 9) + (k8 << 1);
        byte ^= (row & 31) << 4;
        *(u32x4*)(lA + byte) = pk;
    }
    if (t < 128) {
        sb1[t] = b1[t];
        sw2[t] = W2[t];
    }
    __syncthreads();

    const int lane = t & 63;
    const int wave = t >> 6;
    const int cc = lane & 31;     // edge column within tile
    const int h  = lane >> 5;     // k-half
    const float b2v = b2[0];
    const int stride = gridDim.x << 2;
    const int t0 = blockIdx.x * 4 + wave;             // t0 < 2048 <= N_TILES

    Rows A;
    int si, di;                                       // indices for NEXT tile
    {   // prologue: cold gather of tile t0, prefetch ei of t0+stride
        const int e0 = t0 << 5;
        const int s0 = ei[e0 + cc];
        const int d0 = ei[N_EDGES + e0 + cc];
        const unsigned char* ps = (const unsigned char*)(P + ((size_t)s0 << 7));
        const unsigned char* pd = (const unsigned char*)(P + ((size_t)d0 << 7));
#pragma unroll
        for (int kt = 0; kt < 8; ++kt) {
            const int off = (kt << 5) + (h << 4);
            A.v[kt]     = *(const u32x4*)(ps + off);
            A.v[8 + kt] = *(const u32x4*)(pd + off);
        }
        int tt = t0 + stride; tt = tt < N_TILES ? tt : N_TILES - 1;
        si = ei[(tt << 5) + cc];
        di = ei[N_EDGES + (tt << 5) + cc];
    }

    for (int tl = t0; tl < N_TILES; tl += stride) {
        const unsigned char* nps = (const unsigned char*)(P + ((size_t)si << 7));
        const unsigned char* npd = (const unsigned char*)(P + ((size_t)di << 7));

        f32x16 acc[4] = {};
#pragma unroll
        for (int kt = 0; kt < 8; ++kt) {
            const int off = (kt << 5) + (h << 4);
            const u32x4 ux = A.v[kt];
            const u32x4 uy = A.v[8 + kt];
            // rotate: slot kt is dead after the copies above -> refill with
            // tile t+1's chunk kt. Issued ~8 MFMA-blocks before consumption.
            A.v[kt]     = *(const u32x4*)(nps + off);
            A.v[8 + kt] = *(const u32x4*)(npd + off);

            bf16x8 bp, bd;
#pragma unroll
            for (int j = 0; j < 4; ++j) {
                const float x0 = bflo(ux[j]), x1 = bfhi(ux[j]);
                const float y0 = bflo(uy[j]), y1 = bfhi(uy[j]);
                bp[2*j]   = (__bf16)(x0 * y0);
                bp[2*j+1] = (__bf16)(x1 * y1);
                bd[2*j]   = (__bf16)(x0 - y0);
                bd[2*j+1] = (__bf16)(x1 - y1);
            }
#pragma unroll
            for (int t4 = 0; t4 < 4; ++t4) {          // product half: W1[:,0:128]
                const int arow = (t4 << 5) + cc;
                const int ab = ((arow << 9) + off) ^ ((arow & 31) << 4);
                bf16x8 af = __builtin_bit_cast(bf16x8, *(const u32x4*)(lA + ab));
                acc[t4] = __builtin_amdgcn_mfma_f32_32x32x16_bf16(af, bp, acc[t4], 0, 0, 0);
            }
#pragma unroll
            for (int t4 = 0; t4 < 4; ++t4) {          // diff half: W1[:,128:256]
                const int arow = (t4 << 5) + cc;
                const int ab = ((arow << 9) + 256 + off) ^ ((arow & 31) << 4);
                bf16x8 af = __builtin_bit_cast(bf16x8, *(const u32x4*)(lA + ab));
                acc[t4] = __builtin_amdgcn_mfma_f32_32x32x16_bf16(af, bd, acc[t4], 0, 0, 0);
            }
        }

        // epilogue: relu(+b1) . W2 from the LDS side-table (2 addrs/wave =
        // broadcast, conflict-free; lgkm only — no vmem, rotation stays full)
        float partial = 0.f;
#pragma unroll
        for (int t4 = 0; t4 < 4; ++t4) {
#pragma unroll
            for (int q = 0; q < 4; ++q) {
                const int chb = (t4 << 5) + (q << 3) + (h << 2);
                const f32x4 bb = *(const f32x4*)(sb1 + chb);
                const f32x4 ww = *(const f32x4*)(sw2 + chb);
#pragma unroll
                for (int rr = 0; rr < 4; ++rr) {
                    const float hv = fmaxf(acc[t4][(q << 2) + rr] + bb[rr], 0.f);
                    partial += hv * ww[rr];
                }
            }
        }
        partial += __shfl_xor(partial, 32);           // sum the two k-half groups
        const float z = partial + b2v;
        const float prob = 1.0f / (1.0f + __expf(-z));
        if (h == 0) out[(tl << 5) + cc] = prob;

        // advance index prefetch: ei for tile tl + 2*stride
        int tt = tl + 2 * stride; tt = tt < N_TILES ? tt : N_TILES - 1;
        si = ei[(tt << 5) + cc];
        di = ei[N_EDGES + (tt << 5) + cc];
    }
}

extern "C" void kernel_launch(void* const* d_in, const int* in_sizes, int n_in,
                              void* d_out, int out_size, void* d_ws, size_t ws_size,
                              hipStream_t stream) {
    const float* nf   = (const float*)d_in[0];
    const int*   ei   = (const int*)d_in[1];
    const float* Wdim = (const float*)d_in[2];
    const float* bdim = (const float*)d_in[3];
    const float* W1   = (const float*)d_in[4];
    const float* b1   = (const float*)d_in[5];
    const float* W2   = (const float*)d_in[6];
    const float* b2   = (const float*)d_in[7];
    float* out = (float*)d_out;
    unsigned short* P = (unsigned short*)d_ws;        // 100000*128 bf16 = 25.6 MB

    k_project<<<dim3(782), dim3(256), 0, stream>>>(nf, Wdim, bdim, P);
    k_edge<<<dim3(512), dim3(256), 0, stream>>>(P, ei, W1, b1, W2, b2, out);
}

// Round 12
// 455.122 us; speedup vs baseline: 1.4581x; 1.0618x over previous
//
#include <hip/hip_runtime.h>
#include <hip/hip_bf16.h>

// EdgeProbMLP: out[e] = sigmoid( relu( [x*y, x-y] @ W1.T + b1 ) @ W2.T + b2 )
// x = relu(nf[src] @ Wdim.T + bdim), y = same for dst.
// P[n] = relu(proj(nf[n])) precomputed once (bf16, d_ws); per-edge 32x32x16
// MFMA GEMM with W1 in LDS (bf16, XOR-swizzled), plain (L1-allocating)
// gathers, b1/W2 in f32 LDS side-table.
// R12: half-row rotation. R9/R10/R11 triangulated: 2 waves/SIMD needs arch
// VGPR <= 128 quantum WITHOUT spill (acc = 64 AGPR on the unified file);
// R11's live set (~160, Rows=64) spilled 175MB at the 128 cap. Fix: keep
// only 4 of 8 chunks per endpoint row resident (32 VGPR): kt<4 consumes
// chunk kt & refills slot with CURRENT tile chunk kt+4; kt>=4 consumes and
// refills with NEXT tile chunk kt-4. Same 8-deep load burst, prefetch
// distance 4 MFMA-blocks; 2 waves/SIMD cover residual latency. Live ~80-110.
// Falsifier: WRITE~4MB + occupancy ~22% but dur>=190us => line-service wall.

#define N_NODES 100000
#define N_EDGES 1000000
#define N_TILES 31250

typedef unsigned int u32;
typedef u32   u32x2 __attribute__((ext_vector_type(2)));
typedef u32   u32x4 __attribute__((ext_vector_type(4)));
typedef float f32x4 __attribute__((ext_vector_type(4)));
typedef float f32x16 __attribute__((ext_vector_type(16)));
typedef __bf16 bf16x8 __attribute__((ext_vector_type(8)));

__device__ inline u32 pack2bf(float a, float b) {
    unsigned short ua = __builtin_bit_cast(unsigned short, (__bf16)a);
    unsigned short ub = __builtin_bit_cast(unsigned short, (__bf16)b);
    return (u32)ua | ((u32)ub << 16);
}
__device__ inline float bflo(u32 u) { return __builtin_bit_cast(float, u << 16); }
__device__ inline float bfhi(u32 u) { return __builtin_bit_cast(float, u & 0xFFFF0000u); }

// ---------------------------------------------------------------------------
// Kernel 1: P[n][c] = relu(sum_k nf[n][k] * Wdim[c][k] + bdim[c]), bf16 out.
// (unchanged — ~15us, not the bottleneck)
// ---------------------------------------------------------------------------
__global__ __launch_bounds__(256, 1) void k_project(
    const float* __restrict__ nf, const float* __restrict__ Wdim,
    const float* __restrict__ bdim, unsigned short* __restrict__ P)
{
    __shared__ unsigned char lA[128 * 256];  // 32 KB: Wdim as bf16 [128ch][128k]
    const int t = threadIdx.x;
    for (int ci = t; ci < 2048; ci += 256) {          // 2048 chunks of 8 elems
        const int row = ci >> 4;                      // 16 chunks per 128-elem row
        const int k8 = (ci & 15) << 3;
        const float* wp = Wdim + (row << 7) + k8;
        f32x4 v0 = *(const f32x4*)wp;
        f32x4 v1 = *(const f32x4*)(wp + 4);
        u32x4 pk = { pack2bf(v0[0], v0[1]), pack2bf(v0[2], v0[3]),
                     pack2bf(v1[0], v1[1]), pack2bf(v1[2], v1[3]) };
        int byte = (row << 8) + (k8 << 1);
        byte ^= (row & 15) << 4;
        *(u32x4*)(lA + byte) = pk;
    }
    __syncthreads();

    const int lane = t & 63;
    const int wave = t >> 6;
    const int cc = lane & 31;     // node column
    const int h  = lane >> 5;     // k-half within MFMA
    const int tile = blockIdx.x * 4 + wave;
    if (tile >= 3125) return;
    const int node = (tile << 5) + cc;
    const float* xrow = nf + ((size_t)node << 7);

    f32x4 rv[16];
#pragma unroll
    for (int kt = 0; kt < 8; ++kt) {
        const int kf = (kt << 4) + (h << 3);
        rv[2*kt]   = *(const f32x4*)(xrow + kf);
        rv[2*kt+1] = *(const f32x4*)(xrow + kf + 4);
    }

    f32x16 acc[4] = {};
#pragma unroll
    for (int kt = 0; kt < 8; ++kt) {                  // K = 128 = 8 * 16
        const int kf = (kt << 4) + (h << 3);
        f32x4 v0 = rv[2*kt], v1 = rv[2*kt+1];
        bf16x8 bf;
        bf[0]=(__bf16)v0[0]; bf[1]=(__bf16)v0[1]; bf[2]=(__bf16)v0[2]; bf[3]=(__bf16)v0[3];
        bf[4]=(__bf16)v1[0]; bf[5]=(__bf16)v1[1]; bf[6]=(__bf16)v1[2]; bf[7]=(__bf16)v1[3];
        const int off = kf << 1;                      // byte offset within LDS row
#pragma unroll
        for (int t4 = 0; t4 < 4; ++t4) {
            const int arow = (t4 << 5) + cc;
            const int ab = ((arow << 8) + off) ^ ((arow & 15) << 4);
            bf16x8 af = __builtin_bit_cast(bf16x8, *(const u32x4*)(lA + ab));
            acc[t4] = __builtin_amdgcn_mfma_f32_32x32x16_bf16(af, bf, acc[t4], 0, 0, 0);
        }
    }
    unsigned short* prow = P + ((size_t)node << 7);
#pragma unroll
    for (int t4 = 0; t4 < 4; ++t4) {
#pragma unroll
        for (int q = 0; q < 4; ++q) {
            const int chb = (t4 << 5) + (q << 3) + (h << 2);
            f32x4 bb = *(const f32x4*)(bdim + chb);
            const float h0 = fmaxf(acc[t4][(q << 2) + 0] + bb[0], 0.f);
            const float h1 = fmaxf(acc[t4][(q << 2) + 1] + bb[1], 0.f);
            const float h2 = fmaxf(acc[t4][(q << 2) + 2] + bb[2], 0.f);
            const float h3 = fmaxf(acc[t4][(q << 2) + 3] + bb[3], 0.f);
            u32x2 st = { pack2bf(h0, h1), pack2bf(h2, h3) };
            *(u32x2*)(prow + chb) = st;
        }
    }
}

// ---------------------------------------------------------------------------
// Kernel 2: per-edge MLP, 32 edges/wave-tile, half-row rotating prefetch.
// ---------------------------------------------------------------------------
__global__ __launch_bounds__(256, 2) void k_edge(
    const unsigned short* __restrict__ P,
    const int* __restrict__ ei,          // [2][E] int32
    const float* __restrict__ W1, const float* __restrict__ b1,
    const float* __restrict__ W2, const float* __restrict__ b2,
    float* __restrict__ out)
{
    __shared__ unsigned char lA[128 * 512];  // 64 KB: W1 bf16 [128ch][256k]
    __shared__ float sb1[128];               // b1 (f32, exact)
    __shared__ float sw2[128];               // W2 (f32, exact)
    const int t = threadIdx.x;
    for (int ci = t; ci < 4096; ci += 256) {          // 4096 chunks of 8
        const int row = ci >> 5;                      // 32 chunks per 256-elem row
        const int k8 = (ci & 31) << 3;
        const float* wp = W1 + (row << 8) + k8;
        f32x4 v0 = *(const f32x4*)wp;
        f32x4 v1 = *(const f32x4*)(wp + 4);
        u32x4 pk = { pack2bf(v0[0], v0[1]), pack2bf(v0[2], v0[3]),
                     pack2bf(v1[0], v1[1]), pack2bf(v1[2], v1[3]) };
        int byte = (row << 9) + (k8 << 1);
        byte ^= (row & 31) << 4;
        *(u32x4*)(lA + byte) = pk;
    }
    if (t < 128) {
        sb1[t] = b1[t];
        sw2[t] = W2[t];
    }
    __syncthreads();

    const int lane = t & 63;
    const int wave = t >> 6;
    const int cc = lane & 31;     // edge column within tile
    const int h  = lane >> 5;     // k-half
    const float b2v = b2[0];
    const int stride = gridDim.x << 2;
    const int t0 = blockIdx.x * 4 + wave;             // t0 < 2048 <= N_TILES

    u32x4 xr[4], yr[4];           // HALF-row rotation slots (32 VGPR)
    const unsigned char *ps, *pd; // current-tile row bases
    int si, di;                   // node indices for NEXT tile
    {   // prologue: chunks 0..3 of tile t0, prefetch ei of t0+stride
        const int e0 = t0 << 5;
        const int s0 = ei[e0 + cc];
        const int d0 = ei[N_EDGES + e0 + cc];
        ps = (const unsigned char*)(P + ((size_t)s0 << 7));
        pd = (const unsigned char*)(P + ((size_t)d0 << 7));
#pragma unroll
        for (int c = 0; c < 4; ++c) {
            const int off = (c << 5) + (h << 4);
            xr[c] = *(const u32x4*)(ps + off);
            yr[c] = *(const u32x4*)(pd + off);
        }
        int tt = t0 + stride; tt = tt < N_TILES ? tt : N_TILES - 1;
        si = ei[(tt << 5) + cc];
        di = ei[N_EDGES + (tt << 5) + cc];
    }

    for (int tl = t0; tl < N_TILES; tl += stride) {
        const unsigned char* nps = (const unsigned char*)(P + ((size_t)si << 7));
        const unsigned char* npd = (const unsigned char*)(P + ((size_t)di << 7));

        f32x16 acc[4] = {};
#pragma unroll
        for (int kt = 0; kt < 8; ++kt) {
            const int slot = kt & 3;
            const int off = (kt << 5) + (h << 4);
            const u32x4 ux = xr[slot];
            const u32x4 uy = yr[slot];
            // rotate: kt<4 -> refill slot with CURRENT tile chunk kt+4;
            //         kt>=4 -> refill with NEXT tile chunk kt-4.
            if (kt < 4) {
                const int roff = ((kt + 4) << 5) + (h << 4);
                xr[slot] = *(const u32x4*)(ps + roff);
                yr[slot] = *(const u32x4*)(pd + roff);
            } else {
                const int roff = ((kt - 4) << 5) + (h << 4);
                xr[slot] = *(const u32x4*)(nps + roff);
                yr[slot] = *(const u32x4*)(npd + roff);
            }

            bf16x8 bp, bd;
#pragma unroll
            for (int j = 0; j < 4; ++j) {
                const float x0 = bflo(ux[j]), x1 = bfhi(ux[j]);
                const float y0 = bflo(uy[j]), y1 = bfhi(uy[j]);
                bp[2*j]   = (__bf16)(x0 * y0);
                bp[2*j+1] = (__bf16)(x1 * y1);
                bd[2*j]   = (__bf16)(x0 - y0);
                bd[2*j+1] = (__bf16)(x1 - y1);
            }
#pragma unroll
            for (int t4 = 0; t4 < 4; ++t4) {          // product half: W1[:,0:128]
                const int arow = (t4 << 5) + cc;
                const int ab = ((arow << 9) + off) ^ ((arow & 31) << 4);
                bf16x8 af = __builtin_bit_cast(bf16x8, *(const u32x4*)(lA + ab));
                acc[t4] = __builtin_amdgcn_mfma_f32_32x32x16_bf16(af, bp, acc[t4], 0, 0, 0);
            }
#pragma unroll
            for (int t4 = 0; t4 < 4; ++t4) {          // diff half: W1[:,128:256]
                const int arow = (t4 << 5) + cc;
                const int ab = ((arow << 9) + 256 + off) ^ ((arow & 31) << 4);
                bf16x8 af = __builtin_bit_cast(bf16x8, *(const u32x4*)(lA + ab));
                acc[t4] = __builtin_amdgcn_mfma_f32_32x32x16_bf16(af, bd, acc[t4], 0, 0, 0);
            }
        }

        // epilogue: relu(+b1) . W2 from LDS side-table (broadcast, lgkm only)
        float partial = 0.f;
#pragma unroll
        for (int t4 = 0; t4 < 4; ++t4) {
#pragma unroll
            for (int q = 0; q < 4; ++q) {
                const int chb = (t4 << 5) + (q << 3) + (h << 2);
                const f32x4 bb = *(const f32x4*)(sb1 + chb);
                const f32x4 ww = *(const f32x4*)(sw2 + chb);
#pragma unroll
                for (int rr = 0; rr < 4; ++rr) {
                    const float hv = fmaxf(acc[t4][(q << 2) + rr] + bb[rr], 0.f);
                    partial += hv * ww[rr];
                }
            }
        }
        partial += __shfl_xor(partial, 32);           // sum the two k-half groups
        const float z = partial + b2v;
        const float prob = 1.0f / (1.0f + __expf(-z));
        if (h == 0) out[(tl << 5) + cc] = prob;

        // advance: current rows <- next rows; prefetch ei for tl + 2*stride
        ps = nps; pd = npd;
        int tt = tl + 2 * stride; tt = tt < N_TILES ? tt : N_TILES - 1;
        si = ei[(tt << 5) + cc];
        di = ei[N_EDGES + (tt << 5) + cc];
    }
}

extern "C" void kernel_launch(void* const* d_in, const int* in_sizes, int n_in,
                              void* d_out, int out_size, void* d_ws, size_t ws_size,
                              hipStream_t stream) {
    const float* nf   = (const float*)d_in[0];
    const int*   ei   = (const int*)d_in[1];
    const float* Wdim = (const float*)d_in[2];
    const float* bdim = (const float*)d_in[3];
    const float* W1   = (const float*)d_in[4];
    const float* b1   = (const float*)d_in[5];
    const float* W2   = (const float*)d_in[6];
    const float* b2   = (const float*)d_in[7];
    float* out = (float*)d_out;
    unsigned short* P = (unsigned short*)d_ws;        // 100000*128 bf16 = 25.6 MB

    k_project<<<dim3(782), dim3(256), 0, stream>>>(nf, Wdim, bdim, P);
    k_edge<<<dim3(512), dim3(256), 0, stream>>>(P, ei, W1, b1, W2, b2, out);
}

// Round 13
// 190.152 us; speedup vs baseline: 3.4900x; 2.3935x over previous
//
#include <hip/hip_runtime.h>
#include <hip/hip_bf16.h>

// EdgeProbMLP: out[e] = sigmoid( relu( [x*y, x-y] @ W1.T + b1 ) @ W2.T + b2 )
// x = relu(nf[src] @ Wdim.T + bdim), y = same for dst.
// P[n] = relu(proj(nf[n])) precomputed once (bf16, d_ws).
// R13: residency inversion. R9-R12 proved: register-resident gather pipelines
// spill at every launch-bound quantum, and W1's 64KB LDS tile (not VGPRs) was
// what pinned occupancy at 1 block/CU. New structure:
//   - W1 lives in REGISTERS: 4 waves/block each own a 32-channel strip
//     (16 bf16x8 A-frags = 64 VGPR, loaded once per block).
//   - Edge rows gathered ASYNC via global_load_lds (per-lane global source,
//     wave-uniform LDS dest): 4 instrs/wave stage the 32-edge tile's 64 rows
//     (16 KB) into double-buffered LDS. Zero VGPRs of in-flight gather data.
//   - Bank conflicts: source-side chunk swizzle gc = c ^ (r&15), mirrored on
//     ds_read (both-sides rule).
//   - 2-phase pipeline: STAGE(buf^1) -> compute(buf) -> barrier (compiler
//     emits vmcnt(0) before s_barrier => stage has full compute phase to land).
//   - acc = 16 regs/wave; cross-wave channel reduce via LDS partials (dbuf'd).
//   - LDS ~35 KB, regs <=256 @ (256,2) -> 2 blocks/CU = 8 waves (2x R9).

#define N_NODES 100000
#define N_EDGES 1000000
#define NT      31250     // 1M / 32 edges per tile
#define GRID    512       // 2 blocks/CU * 256 CUs

typedef unsigned int u32;
typedef u32   u32x2 __attribute__((ext_vector_type(2)));
typedef u32   u32x4 __attribute__((ext_vector_type(4)));
typedef float f32x4 __attribute__((ext_vector_type(4)));
typedef float f32x16 __attribute__((ext_vector_type(16)));
typedef __bf16 bf16x8 __attribute__((ext_vector_type(8)));

__device__ inline u32 pack2bf(float a, float b) {
    unsigned short ua = __builtin_bit_cast(unsigned short, (__bf16)a);
    unsigned short ub = __builtin_bit_cast(unsigned short, (__bf16)b);
    return (u32)ua | ((u32)ub << 16);
}
__device__ inline float bflo(u32 u) { return __builtin_bit_cast(float, u << 16); }
__device__ inline float bfhi(u32 u) { return __builtin_bit_cast(float, u & 0xFFFF0000u); }

// async gather: per-lane global src, HW writes LDS at (uniform base + lane*16)
__device__ __forceinline__ void gload16(const unsigned char* g, unsigned char* l) {
    __builtin_amdgcn_global_load_lds(
        (__attribute__((address_space(1))) unsigned int*)g,
        (__attribute__((address_space(3))) unsigned int*)l,
        16, 0, 0);
}

// ---------------------------------------------------------------------------
// Kernel 1: P[n][c] = relu(sum_k nf[n][k] * Wdim[c][k] + bdim[c]), bf16 out.
// (unchanged — ~15us, not the bottleneck)
// ---------------------------------------------------------------------------
__global__ __launch_bounds__(256, 1) void k_project(
    const float* __restrict__ nf, const float* __restrict__ Wdim,
    const float* __restrict__ bdim, unsigned short* __restrict__ P)
{
    __shared__ unsigned char lA[128 * 256];  // 32 KB: Wdim as bf16 [128ch][128k]
    const int t = threadIdx.x;
    for (int ci = t; ci < 2048; ci += 256) {
        const int row = ci >> 4;
        const int k8 = (ci & 15) << 3;
        const float* wp = Wdim + (row << 7) + k8;
        f32x4 v0 = *(const f32x4*)wp;
        f32x4 v1 = *(const f32x4*)(wp + 4);
        u32x4 pk = { pack2bf(v0[0], v0[1]), pack2bf(v0[2], v0[3]),
                     pack2bf(v1[0], v1[1]), pack2bf(v1[2], v1[3]) };
        int byte = (row << 8) + (k8 << 1);
        byte ^= (row & 15) << 4;
        *(u32x4*)(lA + byte) = pk;
    }
    __syncthreads();

    const int lane = t & 63;
    const int wave = t >> 6;
    const int cc = lane & 31;
    const int h  = lane >> 5;
    const int tile = blockIdx.x * 4 + wave;
    if (tile >= 3125) return;
    const int node = (tile << 5) + cc;
    const float* xrow = nf + ((size_t)node << 7);

    f32x4 rv[16];
#pragma unroll
    for (int kt = 0; kt < 8; ++kt) {
        const int kf = (kt << 4) + (h << 3);
        rv[2*kt]   = *(const f32x4*)(xrow + kf);
        rv[2*kt+1] = *(const f32x4*)(xrow + kf + 4);
    }

    f32x16 acc[4] = {};
#pragma unroll
    for (int kt = 0; kt < 8; ++kt) {
        const int kf = (kt << 4) + (h << 3);
        f32x4 v0 = rv[2*kt], v1 = rv[2*kt+1];
        bf16x8 bf;
        bf[0]=(__bf16)v0[0]; bf[1]=(__bf16)v0[1]; bf[2]=(__bf16)v0[2]; bf[3]=(__bf16)v0[3];
        bf[4]=(__bf16)v1[0]; bf[5]=(__bf16)v1[1]; bf[6]=(__bf16)v1[2]; bf[7]=(__bf16)v1[3];
        const int off = kf << 1;
#pragma unroll
        for (int t4 = 0; t4 < 4; ++t4) {
            const int arow = (t4 << 5) + cc;
            const int ab = ((arow << 8) + off) ^ ((arow & 15) << 4);
            bf16x8 af = __builtin_bit_cast(bf16x8, *(const u32x4*)(lA + ab));
            acc[t4] = __builtin_amdgcn_mfma_f32_32x32x16_bf16(af, bf, acc[t4], 0, 0, 0);
        }
    }
    unsigned short* prow = P + ((size_t)node << 7);
#pragma unroll
    for (int t4 = 0; t4 < 4; ++t4) {
#pragma unroll
        for (int q = 0; q < 4; ++q) {
            const int chb = (t4 << 5) + (q << 3) + (h << 2);
            f32x4 bb = *(const f32x4*)(bdim + chb);
            const float h0 = fmaxf(acc[t4][(q << 2) + 0] + bb[0], 0.f);
            const float h1 = fmaxf(acc[t4][(q << 2) + 1] + bb[1], 0.f);
            const float h2 = fmaxf(acc[t4][(q << 2) + 2] + bb[2], 0.f);
            const float h3 = fmaxf(acc[t4][(q << 2) + 3] + bb[3], 0.f);
            u32x2 st = { pack2bf(h0, h1), pack2bf(h2, h3) };
            *(u32x2*)(prow + chb) = st;
        }
    }
}

// ---------------------------------------------------------------------------
// Kernel 2: block-cooperative 32-edge tiles. W1 strips in registers; edge
// rows async-gathered into double-buffered LDS via global_load_lds.
// Rows: r=0..31 src (x), r=32..63 dst (y); buf[r][c16] holds global chunk
// c ^ (r&15) (source-side swizzle). Wave w stages rows [w*16, w*16+16).
// ---------------------------------------------------------------------------
__global__ __launch_bounds__(256, 2) void k_edge(
    const unsigned short* __restrict__ P,
    const int* __restrict__ ei,          // [2][E] int32
    const float* __restrict__ W1, const float* __restrict__ b1,
    const float* __restrict__ W2, const float* __restrict__ b2,
    float* __restrict__ out)
{
    __shared__ unsigned char buf[2][64 * 256];   // 32 KB: 2 x 64 rows x 256B
    __shared__ float pr[2][4][32];               // per-wave partials (dbuf)
    __shared__ float sb1[128], sw2[128];
    const int t = threadIdx.x;
    const int lane = t & 63;
    const int wave = t >> 6;
    const int cc = lane & 31;     // edge column / A-row
    const int h  = lane >> 5;     // k-half
    if (t < 128) { sb1[t] = b1[t]; sw2[t] = W2[t]; }

    // ---- W1 strip -> registers: wave w owns channels [w*32, w*32+32).
    // A-frag (kt,half): lane cc holds W1[w*32+cc][half*128 + kt*16 + h*8 .. +8]
    bf16x8 wf[16];
    {
        const float* wrow = W1 + (((wave << 5) + cc) << 8);   // 256 f32/row
#pragma unroll
        for (int kt = 0; kt < 8; ++kt) {
#pragma unroll
            for (int half = 0; half < 2; ++half) {
                const float* wp = wrow + (half << 7) + (kt << 4) + (h << 3);
                f32x4 a = *(const f32x4*)wp;
                f32x4 b = *(const f32x4*)(wp + 4);
                bf16x8 f;
                f[0]=(__bf16)a[0]; f[1]=(__bf16)a[1]; f[2]=(__bf16)a[2]; f[3]=(__bf16)a[3];
                f[4]=(__bf16)b[0]; f[5]=(__bf16)b[1]; f[6]=(__bf16)b[2]; f[7]=(__bf16)b[3];
                wf[(kt << 1) + half] = f;
            }
        }
    }

    // lane-constant staging geometry: instr i covers rows w*16+i*4+(lane>>4),
    // slot chunk c = lane&15, global chunk = c ^ (r&15)  (w*16 == 0 mod 16)
    const unsigned char* Pb = (const unsigned char*)P;
    const int* eb = ei + (wave < 2 ? 0 : N_EDGES - 32);   // dst waves offset
    int xo[4], rbase[4];
#pragma unroll
    for (int i = 0; i < 4; ++i) {
        const int rl = (i << 2) + (lane >> 4);            // r mod 16
        xo[i] = ((lane & 15) ^ (rl & 15)) << 4;
        rbase[i] = (wave << 4) + rl;                      // row within 0..63
    }
    const float b2v = b2[0];
    const int t0 = blockIdx.x;

    // ---- prologue: stage tile t0 into buf[0]; prefetch idx for t0+GRID
    int nidx0, nidx1, nidx2, nidx3;
    {
        int i0 = eb[(t0 << 5) + rbase[0]];
        int i1 = eb[(t0 << 5) + rbase[1]];
        int i2 = eb[(t0 << 5) + rbase[2]];
        int i3 = eb[(t0 << 5) + rbase[3]];
        gload16(Pb + ((size_t)i0 << 8) + xo[0], &buf[0][(rbase[0] & ~3) << 8]);
        gload16(Pb + ((size_t)i1 << 8) + xo[1], &buf[0][(rbase[1] & ~3) << 8]);
        gload16(Pb + ((size_t)i2 << 8) + xo[2], &buf[0][(rbase[2] & ~3) << 8]);
        gload16(Pb + ((size_t)i3 << 8) + xo[3], &buf[0][(rbase[3] & ~3) << 8]);
        int tn = t0 + GRID; tn = tn < NT ? tn : NT - 1;
        nidx0 = eb[(tn << 5) + rbase[0]];
        nidx1 = eb[(tn << 5) + rbase[1]];
        nidx2 = eb[(tn << 5) + rbase[2]];
        nidx3 = eb[(tn << 5) + rbase[3]];
    }
    __syncthreads();   // buf[0] staged (vmcnt drained), sb1/sw2 ready

    int p = 0;
    for (int tl = t0; tl < NT; tl += GRID) {
        // ---- STAGE next tile into buf[p^1] (async, zero VGPR payload)
        unsigned char* nb = buf[p ^ 1];
        gload16(Pb + ((size_t)nidx0 << 8) + xo[0], nb + ((rbase[0] & ~3) << 8));
        gload16(Pb + ((size_t)nidx1 << 8) + xo[1], nb + ((rbase[1] & ~3) << 8));
        gload16(Pb + ((size_t)nidx2 << 8) + xo[2], nb + ((rbase[2] & ~3) << 8));
        gload16(Pb + ((size_t)nidx3 << 8) + xo[3], nb + ((rbase[3] & ~3) << 8));
        // prefetch indices for tile tl + 2*GRID
        {
            int tn = tl + 2 * GRID; tn = tn < NT ? tn : NT - 1;
            nidx0 = eb[(tn << 5) + rbase[0]];
            nidx1 = eb[(tn << 5) + rbase[1]];
            nidx2 = eb[(tn << 5) + rbase[2]];
            nidx3 = eb[(tn << 5) + rbase[3]];
        }

        // ---- compute tile tl from buf[p]
        const unsigned char* bp_ = buf[p];
        const unsigned char* xb = bp_ + (cc << 8);            // src row cc
        const unsigned char* yb = bp_ + ((32 + cc) << 8);     // dst row cc
        const int cx = cc & 15;
        f32x16 acc = {};
#pragma unroll
        for (int kt = 0; kt < 8; ++kt) {
            const int co = (((kt << 1) + h) ^ cx) << 4;       // swizzled chunk
            const u32x4 ux = *(const u32x4*)(xb + co);
            const u32x4 uy = *(const u32x4*)(yb + co);
            bf16x8 bp, bd;
#pragma unroll
            for (int j = 0; j < 4; ++j) {
                const float x0 = bflo(ux[j]), x1 = bfhi(ux[j]);
                const float y0 = bflo(uy[j]), y1 = bfhi(uy[j]);
                bp[2*j]   = (__bf16)(x0 * y0);
                bp[2*j+1] = (__bf16)(x1 * y1);
                bd[2*j]   = (__bf16)(x0 - y0);
                bd[2*j+1] = (__bf16)(x1 - y1);
            }
            acc = __builtin_amdgcn_mfma_f32_32x32x16_bf16(wf[(kt << 1) + 0], bp, acc, 0, 0, 0);
            acc = __builtin_amdgcn_mfma_f32_32x32x16_bf16(wf[(kt << 1) + 1], bd, acc, 0, 0, 0);
        }

        // ---- epilogue: relu(+b1).W2 for this wave's 32-channel strip
        // D: edge = cc, ch_local = (r&3) + 8*(r>>2) + 4*h
        float partial = 0.f;
#pragma unroll
        for (int q = 0; q < 4; ++q) {
            const int chb = (wave << 5) + (q << 3) + (h << 2);
            const f32x4 bb = *(const f32x4*)(sb1 + chb);
            const f32x4 ww = *(const f32x4*)(sw2 + chb);
#pragma unroll
            for (int rr = 0; rr < 4; ++rr) {
                const float hv = fmaxf(acc[(q << 2) + rr] + bb[rr], 0.f);
                partial += hv * ww[rr];
            }
        }
        partial += __shfl_xor(partial, 32);       // sum the two k-halves
        if (h == 0) pr[p][wave][cc] = partial;

        __syncthreads();   // pr[p] visible; buf[p^1] staged (vmcnt drained)

        if (t < 32) {      // wave 0, lanes 0..31: finish + store tile tl
            const float z = pr[p][0][t] + pr[p][1][t] + pr[p][2][t] + pr[p][3][t] + b2v;
            out[(tl << 5) + t] = 1.0f / (1.0f + __expf(-z));
        }
        p ^= 1;
    }
}

extern "C" void kernel_launch(void* const* d_in, const int* in_sizes, int n_in,
                              void* d_out, int out_size, void* d_ws, size_t ws_size,
                              hipStream_t stream) {
    const float* nf   = (const float*)d_in[0];
    const int*   ei   = (const int*)d_in[1];
    const float* Wdim = (const float*)d_in[2];
    const float* bdim = (const float*)d_in[3];
    const float* W1   = (const float*)d_in[4];
    const float* b1   = (const float*)d_in[5];
    const float* W2   = (const float*)d_in[6];
    const float* b2   = (const float*)d_in[7];
    float* out = (float*)d_out;
    unsigned short* P = (unsigned short*)d_ws;        // 100000*128 bf16 = 25.6 MB

    k_project<<<dim3(782), dim3(256), 0, stream>>>(nf, Wdim, bdim, P);
    k_edge<<<dim3(GRID), dim3(256), 0, stream>>>(P, ei, W1, b1, W2, b2, out);
}

// Round 14
// 149.610 us; speedup vs baseline: 4.4357x; 1.2710x over previous
//
#include <hip/hip_runtime.h>
#include <hip/hip_bf16.h>

// EdgeProbMLP: out[e] = sigmoid( relu( [x*y, x-y] @ W1.T + b1 ) @ W2.T + b2 )
// x = relu(nf[src] @ Wdim.T + bdim), y = same for dst.
// P[n] = relu(proj(nf[n])) precomputed once (f16, d_ws).
// R14 = R13 structure (W1 strips in registers, async global_load_lds gather
// into double-buffered LDS, source-side chunk swizzle, 2-phase pipeline)
// with the VALU hot loop moved to f16 PACKED math: R13 counters showed
// VALUBusy 55.9% vs MfmaUtil 15.3% — the unpack(bf16->f32)/mul/sub/repack
// chain (~48 VALU ops/kt) dominated. P stored as f16; B-fragments built as
// f16x8 vector mul/sub -> v_pk_mul_f16/v_pk_add_f16 (8 ops/kt, 6x less);
// MFMA switched to mfma_f32_32x32x16_f16. Precision improves (f16: 10
// mantissa bits vs bf16: 7; range fine — relu outputs <=~8).

#define N_NODES 100000
#define N_EDGES 1000000
#define NT      31250     // 1M / 32 edges per tile
#define GRID    512       // 2 blocks/CU * 256 CUs

typedef unsigned int u32;
typedef u32   u32x2 __attribute__((ext_vector_type(2)));
typedef u32   u32x4 __attribute__((ext_vector_type(4)));
typedef float f32x4 __attribute__((ext_vector_type(4)));
typedef float f32x16 __attribute__((ext_vector_type(16)));
typedef __bf16 bf16x8 __attribute__((ext_vector_type(8)));
typedef _Float16 f16x8 __attribute__((ext_vector_type(8)));

__device__ inline u32 pack2bf(float a, float b) {
    unsigned short ua = __builtin_bit_cast(unsigned short, (__bf16)a);
    unsigned short ub = __builtin_bit_cast(unsigned short, (__bf16)b);
    return (u32)ua | ((u32)ub << 16);
}
__device__ inline u32 pack2h(float a, float b) {
    unsigned short ua = __builtin_bit_cast(unsigned short, (_Float16)a);
    unsigned short ub = __builtin_bit_cast(unsigned short, (_Float16)b);
    return (u32)ua | ((u32)ub << 16);
}

// async gather: per-lane global src, HW writes LDS at (uniform base + lane*16)
__device__ __forceinline__ void gload16(const unsigned char* g, unsigned char* l) {
    __builtin_amdgcn_global_load_lds(
        (__attribute__((address_space(1))) unsigned int*)g,
        (__attribute__((address_space(3))) unsigned int*)l,
        16, 0, 0);
}

// ---------------------------------------------------------------------------
// Kernel 1: P[n][c] = relu(sum_k nf[n][k] * Wdim[c][k] + bdim[c]), F16 out.
// (bf16 MFMA internally — proven path; only the store format changed)
// ---------------------------------------------------------------------------
__global__ __launch_bounds__(256, 1) void k_project(
    const float* __restrict__ nf, const float* __restrict__ Wdim,
    const float* __restrict__ bdim, unsigned short* __restrict__ P)
{
    __shared__ unsigned char lA[128 * 256];  // 32 KB: Wdim as bf16 [128ch][128k]
    const int t = threadIdx.x;
    for (int ci = t; ci < 2048; ci += 256) {
        const int row = ci >> 4;
        const int k8 = (ci & 15) << 3;
        const float* wp = Wdim + (row << 7) + k8;
        f32x4 v0 = *(const f32x4*)wp;
        f32x4 v1 = *(const f32x4*)(wp + 4);
        u32x4 pk = { pack2bf(v0[0], v0[1]), pack2bf(v0[2], v0[3]),
                     pack2bf(v1[0], v1[1]), pack2bf(v1[2], v1[3]) };
        int byte = (row << 8) + (k8 << 1);
        byte ^= (row & 15) << 4;
        *(u32x4*)(lA + byte) = pk;
    }
    __syncthreads();

    const int lane = t & 63;
    const int wave = t >> 6;
    const int cc = lane & 31;
    const int h  = lane >> 5;
    const int tile = blockIdx.x * 4 + wave;
    if (tile >= 3125) return;
    const int node = (tile << 5) + cc;
    const float* xrow = nf + ((size_t)node << 7);

    f32x4 rv[16];
#pragma unroll
    for (int kt = 0; kt < 8; ++kt) {
        const int kf = (kt << 4) + (h << 3);
        rv[2*kt]   = *(const f32x4*)(xrow + kf);
        rv[2*kt+1] = *(const f32x4*)(xrow + kf + 4);
    }

    f32x16 acc[4] = {};
#pragma unroll
    for (int kt = 0; kt < 8; ++kt) {
        const int kf = (kt << 4) + (h << 3);
        f32x4 v0 = rv[2*kt], v1 = rv[2*kt+1];
        bf16x8 bf;
        bf[0]=(__bf16)v0[0]; bf[1]=(__bf16)v0[1]; bf[2]=(__bf16)v0[2]; bf[3]=(__bf16)v0[3];
        bf[4]=(__bf16)v1[0]; bf[5]=(__bf16)v1[1]; bf[6]=(__bf16)v1[2]; bf[7]=(__bf16)v1[3];
        const int off = kf << 1;
#pragma unroll
        for (int t4 = 0; t4 < 4; ++t4) {
            const int arow = (t4 << 5) + cc;
            const int ab = ((arow << 8) + off) ^ ((arow & 15) << 4);
            bf16x8 af = __builtin_bit_cast(bf16x8, *(const u32x4*)(lA + ab));
            acc[t4] = __builtin_amdgcn_mfma_f32_32x32x16_bf16(af, bf, acc[t4], 0, 0, 0);
        }
    }
    unsigned short* prow = P + ((size_t)node << 7);
#pragma unroll
    for (int t4 = 0; t4 < 4; ++t4) {
#pragma unroll
        for (int q = 0; q < 4; ++q) {
            const int chb = (t4 << 5) + (q << 3) + (h << 2);
            f32x4 bb = *(const f32x4*)(bdim + chb);
            const float h0 = fmaxf(acc[t4][(q << 2) + 0] + bb[0], 0.f);
            const float h1 = fmaxf(acc[t4][(q << 2) + 1] + bb[1], 0.f);
            const float h2 = fmaxf(acc[t4][(q << 2) + 2] + bb[2], 0.f);
            const float h3 = fmaxf(acc[t4][(q << 2) + 3] + bb[3], 0.f);
            u32x2 st = { pack2h(h0, h1), pack2h(h2, h3) };   // F16 store
            *(u32x2*)(prow + chb) = st;
        }
    }
}

// ---------------------------------------------------------------------------
// Kernel 2: block-cooperative 32-edge tiles, f16 packed math.
// W1 strips (f16) in registers; edge rows async-gathered into dbuf'd LDS.
// Rows: r=0..31 src (x), r=32..63 dst (y); buf[r][c16] holds global chunk
// c ^ (r&15) (source-side swizzle). Wave w stages rows [w*16, w*16+16).
// ---------------------------------------------------------------------------
__global__ __launch_bounds__(256, 2) void k_edge(
    const unsigned short* __restrict__ P,
    const int* __restrict__ ei,          // [2][E] int32
    const float* __restrict__ W1, const float* __restrict__ b1,
    const float* __restrict__ W2, const float* __restrict__ b2,
    float* __restrict__ out)
{
    __shared__ unsigned char buf[2][64 * 256];   // 32 KB: 2 x 64 rows x 256B
    __shared__ float pr[2][4][32];               // per-wave partials (dbuf)
    __shared__ float sb1[128], sw2[128];
    const int t = threadIdx.x;
    const int lane = t & 63;
    const int wave = t >> 6;
    const int cc = lane & 31;     // edge column / A-row
    const int h  = lane >> 5;     // k-half
    if (t < 128) { sb1[t] = b1[t]; sw2[t] = W2[t]; }

    // ---- W1 strip -> f16 registers: wave w owns channels [w*32, w*32+32).
    f16x8 wf[16];
    {
        const float* wrow = W1 + (((wave << 5) + cc) << 8);   // 256 f32/row
#pragma unroll
        for (int kt = 0; kt < 8; ++kt) {
#pragma unroll
            for (int half = 0; half < 2; ++half) {
                const float* wp = wrow + (half << 7) + (kt << 4) + (h << 3);
                f32x4 a = *(const f32x4*)wp;
                f32x4 b = *(const f32x4*)(wp + 4);
                f16x8 f;
                f[0]=(_Float16)a[0]; f[1]=(_Float16)a[1]; f[2]=(_Float16)a[2]; f[3]=(_Float16)a[3];
                f[4]=(_Float16)b[0]; f[5]=(_Float16)b[1]; f[6]=(_Float16)b[2]; f[7]=(_Float16)b[3];
                wf[(kt << 1) + half] = f;
            }
        }
    }

    // lane-constant staging geometry: instr i covers rows w*16+i*4+(lane>>4),
    // slot chunk c = lane&15, global chunk = c ^ (r&15)
    const unsigned char* Pb = (const unsigned char*)P;
    const int* eb = ei + (wave < 2 ? 0 : N_EDGES - 32);   // dst waves offset
    int xo[4], rbase[4];
#pragma unroll
    for (int i = 0; i < 4; ++i) {
        const int rl = (i << 2) + (lane >> 4);            // r mod 16
        xo[i] = ((lane & 15) ^ (rl & 15)) << 4;
        rbase[i] = (wave << 4) + rl;                      // row within 0..63
    }
    const float b2v = b2[0];
    const int t0 = blockIdx.x;

    // ---- prologue: stage tile t0 into buf[0]; prefetch idx for t0+GRID
    int nidx0, nidx1, nidx2, nidx3;
    {
        int i0 = eb[(t0 << 5) + rbase[0]];
        int i1 = eb[(t0 << 5) + rbase[1]];
        int i2 = eb[(t0 << 5) + rbase[2]];
        int i3 = eb[(t0 << 5) + rbase[3]];
        gload16(Pb + ((size_t)i0 << 8) + xo[0], &buf[0][(rbase[0] & ~3) << 8]);
        gload16(Pb + ((size_t)i1 << 8) + xo[1], &buf[0][(rbase[1] & ~3) << 8]);
        gload16(Pb + ((size_t)i2 << 8) + xo[2], &buf[0][(rbase[2] & ~3) << 8]);
        gload16(Pb + ((size_t)i3 << 8) + xo[3], &buf[0][(rbase[3] & ~3) << 8]);
        int tn = t0 + GRID; tn = tn < NT ? tn : NT - 1;
        nidx0 = eb[(tn << 5) + rbase[0]];
        nidx1 = eb[(tn << 5) + rbase[1]];
        nidx2 = eb[(tn << 5) + rbase[2]];
        nidx3 = eb[(tn << 5) + rbase[3]];
    }
    __syncthreads();   // buf[0] staged (vmcnt drained), sb1/sw2 ready

    int p = 0;
    for (int tl = t0; tl < NT; tl += GRID) {
        // ---- STAGE next tile into buf[p^1] (async, zero VGPR payload)
        unsigned char* nb = buf[p ^ 1];
        gload16(Pb + ((size_t)nidx0 << 8) + xo[0], nb + ((rbase[0] & ~3) << 8));
        gload16(Pb + ((size_t)nidx1 << 8) + xo[1], nb + ((rbase[1] & ~3) << 8));
        gload16(Pb + ((size_t)nidx2 << 8) + xo[2], nb + ((rbase[2] & ~3) << 8));
        gload16(Pb + ((size_t)nidx3 << 8) + xo[3], nb + ((rbase[3] & ~3) << 8));
        // prefetch indices for tile tl + 2*GRID
        {
            int tn = tl + 2 * GRID; tn = tn < NT ? tn : NT - 1;
            nidx0 = eb[(tn << 5) + rbase[0]];
            nidx1 = eb[(tn << 5) + rbase[1]];
            nidx2 = eb[(tn << 5) + rbase[2]];
            nidx3 = eb[(tn << 5) + rbase[3]];
        }

        // ---- compute tile tl from buf[p]: f16 packed mul/sub -> f16 MFMA
        const unsigned char* bp_ = buf[p];
        const unsigned char* xb = bp_ + (cc << 8);            // src row cc
        const unsigned char* yb = bp_ + ((32 + cc) << 8);     // dst row cc
        const int cx = cc & 15;
        f32x16 acc = {};
#pragma unroll
        for (int kt = 0; kt < 8; ++kt) {
            const int co = (((kt << 1) + h) ^ cx) << 4;       // swizzled chunk
            const f16x8 xh = __builtin_bit_cast(f16x8, *(const u32x4*)(xb + co));
            const f16x8 yh = __builtin_bit_cast(f16x8, *(const u32x4*)(yb + co));
            const f16x8 bp = xh * yh;     // 4x v_pk_mul_f16
            const f16x8 bd = xh - yh;     // 4x v_pk_add_f16 (sub)
            acc = __builtin_amdgcn_mfma_f32_32x32x16_f16(wf[(kt << 1) + 0], bp, acc, 0, 0, 0);
            acc = __builtin_amdgcn_mfma_f32_32x32x16_f16(wf[(kt << 1) + 1], bd, acc, 0, 0, 0);
        }

        // ---- epilogue: relu(+b1).W2 for this wave's 32-channel strip
        float partial = 0.f;
#pragma unroll
        for (int q = 0; q < 4; ++q) {
            const int chb = (wave << 5) + (q << 3) + (h << 2);
            const f32x4 bb = *(const f32x4*)(sb1 + chb);
            const f32x4 ww = *(const f32x4*)(sw2 + chb);
#pragma unroll
            for (int rr = 0; rr < 4; ++rr) {
                const float hv = fmaxf(acc[(q << 2) + rr] + bb[rr], 0.f);
                partial += hv * ww[rr];
            }
        }
        partial += __shfl_xor(partial, 32);       // sum the two k-halves
        if (h == 0) pr[p][wave][cc] = partial;

        __syncthreads();   // pr[p] visible; buf[p^1] staged (vmcnt drained)

        if (t < 32) {      // wave 0, lanes 0..31: finish + store tile tl
            const float z = pr[p][0][t] + pr[p][1][t] + pr[p][2][t] + pr[p][3][t] + b2v;
            out[(tl << 5) + t] = 1.0f / (1.0f + __expf(-z));
        }
        p ^= 1;
    }
}

extern "C" void kernel_launch(void* const* d_in, const int* in_sizes, int n_in,
                              void* d_out, int out_size, void* d_ws, size_t ws_size,
                              hipStream_t stream) {
    const float* nf   = (const float*)d_in[0];
    const int*   ei   = (const int*)d_in[1];
    const float* Wdim = (const float*)d_in[2];
    const float* bdim = (const float*)d_in[3];
    const float* W1   = (const float*)d_in[4];
    const float* b1   = (const float*)d_in[5];
    const float* W2   = (const float*)d_in[6];
    const float* b2   = (const float*)d_in[7];
    float* out = (float*)d_out;
    unsigned short* P = (unsigned short*)d_ws;        // 100000*128 f16 = 25.6 MB

    k_project<<<dim3(782), dim3(256), 0, stream>>>(nf, Wdim, bdim, P);
    k_edge<<<dim3(GRID), dim3(256), 0, stream>>>(P, ei, W1, b1, W2, b2, out);
}